// Round 16
// baseline (340.327 us; speedup 1.0000x reference)
//
#include <hip/hip_runtime.h>
#include <hip/hip_bf16.h>

// bf16 pipeline (verified R15: 271.6us, absmax 7.8e-3). This round: fuse the
// two mean-agg gathers INTO the MFMA GEMMs (removes tbuf/t2 round-trips and
// two dispatch barriers; gather overlaps MFMA via co-resident blocks):
//   mg1_k: h   = relu(xb@W1r + gatherMean(xb)@W1l + b1)
//   mgemm: hl  = h@W2l
//   mg3_k: out = h@W2r + gatherMean(hl) + b2
// CSR build: histogram -> scan -> two-phase bucketed fill (R13, verified).

typedef __attribute__((ext_vector_type(8))) short bf16x8;
typedef __attribute__((ext_vector_type(4))) float f32x4;

__device__ __forceinline__ ushort f2b(float f) {            // RNE fp32->bf16
    uint u = __float_as_uint(f);
    return (ushort)((u + 0x7fffu + ((u >> 16) & 1u)) >> 16);
}
__device__ __forceinline__ float b2f(ushort h) { return __uint_as_float(((uint)h) << 16); }
__device__ __forceinline__ float blo(uint u) { return __uint_as_float(u << 16); }
__device__ __forceinline__ float bhi(uint u) { return __uint_as_float(u & 0xffff0000u); }

// ---------------- CSR build ----------------
__global__ void count_deg_k(const int* __restrict__ dstv, int* __restrict__ cnt, int E) {
    int e = blockIdx.x * blockDim.x + threadIdx.x;
    if (e < E) atomicAdd(&cnt[dstv[e]], 1);
}

__global__ __launch_bounds__(256) void blocksum_k(const int* __restrict__ cnt,
                                                  int* __restrict__ bsum, int n) {
    __shared__ int red[4];
    int b = blockIdx.x, t = threadIdx.x;
    int base = b * 1024 + t * 4;
    int s = 0;
    #pragma unroll
    for (int i = 0; i < 4; ++i) { int idx = base + i; if (idx < n) s += cnt[idx]; }
    #pragma unroll
    for (int off = 32; off > 0; off >>= 1) s += __shfl_down(s, off);
    if ((t & 63) == 0) red[t >> 6] = s;
    __syncthreads();
    if (t == 0) bsum[b] = red[0] + red[1] + red[2] + red[3];
}

__global__ __launch_bounds__(256) void bscan_k(int* __restrict__ bsum, int nb) {
    __shared__ int sd[256];
    int t = threadIdx.x;
    int v = (t < nb) ? bsum[t] : 0;
    sd[t] = v;
    __syncthreads();
    for (int off = 1; off < 256; off <<= 1) {
        int u = (t >= off) ? sd[t - off] : 0;
        __syncthreads();
        sd[t] += u;
        __syncthreads();
    }
    if (t < nb) bsum[t] = sd[t] - v;
}

__global__ __launch_bounds__(256) void scanout_k(const int* __restrict__ cnt,
                                                 const int* __restrict__ bbase,
                                                 int* __restrict__ rowptr,
                                                 int* __restrict__ pos,
                                                 float* __restrict__ inv_deg,
                                                 int n, int E) {
    __shared__ int sums[256];
    int b = blockIdx.x, t = threadIdx.x;
    int base = b * 1024 + t * 4;
    int v[4];
    int s = 0;
    #pragma unroll
    for (int i = 0; i < 4; ++i) {
        int idx = base + i;
        v[i] = (idx < n) ? cnt[idx] : 0;
        s += v[i];
    }
    sums[t] = s;
    __syncthreads();
    for (int off = 1; off < 256; off <<= 1) {
        int u = (t >= off) ? sums[t - off] : 0;
        __syncthreads();
        sums[t] += u;
        __syncthreads();
    }
    int pre = sums[t] - s + bbase[b];
    #pragma unroll
    for (int i = 0; i < 4; ++i) {
        int idx = base + i;
        if (idx < n) {
            rowptr[idx] = pre;
            pos[idx] = pre;
            inv_deg[idx] = 1.0f / (float)max(v[i], 1);
            pre += v[i];
        }
    }
    if (b == 0 && t == 0) rowptr[n] = E;
}

__global__ void bucketbase_k(const int* __restrict__ rowptr, int* __restrict__ bucketPos,
                             int nbuckets) {
    int b = blockIdx.x * blockDim.x + threadIdx.x;
    if (b < nbuckets) bucketPos[b] = rowptr[b * 256];
}

__global__ __launch_bounds__(256) void bucket_k(const int* __restrict__ srcv,
                                                const int* __restrict__ dstv,
                                                int* __restrict__ bucketPos,
                                                uint2* __restrict__ ebuf, int E) {
    __shared__ int hist[256], rbase[256];
    int t = threadIdx.x;
    int e0 = blockIdx.x * 2048;
    hist[t] = 0;
    __syncthreads();
    int d[8], s[8];
    #pragma unroll
    for (int i = 0; i < 8; ++i) {
        int e = e0 + t + 256 * i;
        if (e < E) {
            d[i] = dstv[e]; s[i] = srcv[e];
            atomicAdd(&hist[d[i] >> 8], 1);
        } else d[i] = -1;
    }
    __syncthreads();
    if (hist[t] > 0) rbase[t] = atomicAdd(&bucketPos[t], hist[t]);
    __syncthreads();
    hist[t] = 0;
    __syncthreads();
    #pragma unroll
    for (int i = 0; i < 8; ++i) {
        if (d[i] >= 0) {
            int b = d[i] >> 8;
            int off = atomicAdd(&hist[b], 1);
            ebuf[rbase[b] + off] = make_uint2((uint)d[i], (uint)s[i]);
        }
    }
}

__global__ void fill2_k(const uint2* __restrict__ ebuf, int* __restrict__ pos,
                        int* __restrict__ csr, int E) {
    int e = blockIdx.x * blockDim.x + threadIdx.x;
    if (e < E) {
        uint2 v = ebuf[e];
        int p = atomicAdd(&pos[v.x], 1);
        csr[p] = (int)v.y;
    }
}

// ---------------- dtype prep ----------------
__global__ void castx_k(const float* __restrict__ x, ushort* __restrict__ xb, int total4) {
    int i = blockIdx.x * blockDim.x + threadIdx.x;
    if (i < total4) {
        float4 v = reinterpret_cast<const float4*>(x)[i];
        ushort4 r;
        r.x = f2b(v.x); r.y = f2b(v.y); r.z = f2b(v.z); r.w = f2b(v.w);
        reinterpret_cast<ushort4*>(xb)[i] = r;
    }
}

__global__ void prepw_k(const float* __restrict__ W1l, const float* __restrict__ W1r,
                        const float* __restrict__ W2l, const float* __restrict__ W2r,
                        ushort* __restrict__ w1lt, ushort* __restrict__ w1rt,
                        ushort* __restrict__ w2lt, ushort* __restrict__ w2rt) {
    int i = blockIdx.x * blockDim.x + threadIdx.x;   // 0..49151
    if (i < 16384) {
        int nn = i >> 7, k = i & 127;
        w1lt[i] = f2b(W1l[k * 128 + nn]);
    } else if (i < 32768) {
        int j = i - 16384, nn = j >> 7, k = j & 127;
        w1rt[j] = f2b(W1r[k * 128 + nn]);
    } else if (i < 40960) {
        int j = i - 32768, nn = j >> 7, k = j & 127;
        w2lt[j] = f2b(W2l[k * 64 + nn]);
    } else if (i < 49152) {
        int j = i - 40960, nn = j >> 7, k = j & 127;
        w2rt[j] = f2b(W2r[k * 64 + nn]);
    }
}

// ---------------- fused layer 1: h = relu(xb@W1r + gatherMean(xb)@W1l + b1) ----------------
// 64 rows/block, 4 waves. Phase 1: MFMA xb@W1r. Phase 2: half-wave-per-node
// gather (4-edge unroll) writes bf16 mean rows into the LDS A-tile; stage W1l;
// MFMA. Epilogue bias+relu -> bf16 h. Arithmetic identical to aggb_k+mgemm.
__global__ __launch_bounds__(256) void mg1_k(const ushort* __restrict__ xb,
                                             const ushort* __restrict__ w1rt,
                                             const ushort* __restrict__ w1lt,
                                             const int* __restrict__ rowptr,
                                             const int* __restrict__ csr,
                                             const float* __restrict__ invd,
                                             const float* __restrict__ b1,
                                             ushort* __restrict__ h, int n) {
    constexpr int AST = 136;
    __shared__ ushort At[64 * AST];
    __shared__ ushort Bt[128 * AST];
    int t = threadIdx.x;
    int brow = blockIdx.x * 64;
    int w = t >> 6, l = t & 63, lrow = l & 15, lk = l >> 4;

    f32x4 acc[8];
    #pragma unroll
    for (int g = 0; g < 8; ++g) acc[g] = (f32x4){0.f, 0.f, 0.f, 0.f};

    // stage At = xb tile, Bt = W1r^T
    #pragma unroll
    for (int i = 0; i < 4; ++i) {
        int c = t + 256 * i, r = c >> 4, k16 = c & 15;
        int grow = brow + r;
        uint4 v = make_uint4(0, 0, 0, 0);
        if (grow < n) v = *reinterpret_cast<const uint4*>(&xb[(size_t)grow * 128 + k16 * 8]);
        *reinterpret_cast<uint4*>(&At[r * AST + k16 * 8]) = v;
    }
    #pragma unroll
    for (int i = 0; i < 8; ++i) {
        int c = t + 256 * i, r = c >> 4, k16 = c & 15;
        *reinterpret_cast<uint4*>(&Bt[r * AST + k16 * 8]) =
            *reinterpret_cast<const uint4*>(&w1rt[(size_t)r * 128 + k16 * 8]);
    }
    __syncthreads();
    #pragma unroll
    for (int ks = 0; ks < 4; ++ks) {
        bf16x8 a = *reinterpret_cast<const bf16x8*>(&At[(w * 16 + lrow) * AST + ks * 32 + lk * 8]);
        #pragma unroll
        for (int g = 0; g < 8; ++g) {
            bf16x8 b = *reinterpret_cast<const bf16x8*>(&Bt[(g * 16 + lrow) * AST + ks * 32 + lk * 8]);
            acc[g] = __builtin_amdgcn_mfma_f32_16x16x32_bf16(a, b, acc[g], 0, 0, 0);
        }
    }
    __syncthreads();   // all LDS reads of phase 1 complete before overwrite

    // gather phase: half-wave (32 lanes) per node, 8 nodes each; lane owns 8B
    int hw = t >> 5, sl = t & 31;
    for (int i = 0; i < 8; ++i) {
        int lr = i * 8 + hw;
        int node = brow + lr;
        float a0 = 0, a1 = 0, a2 = 0, a3 = 0;
        if (node < n) {
            int s = rowptr[node], e = rowptr[node + 1];
            float sc = invd[node];
            int p = s;
            for (; p + 4 <= e; p += 4) {
                int u0 = csr[p], u1 = csr[p + 1], u2 = csr[p + 2], u3 = csr[p + 3];
                uint2 v0 = *reinterpret_cast<const uint2*>(&xb[(size_t)u0 * 128 + sl * 4]);
                uint2 v1 = *reinterpret_cast<const uint2*>(&xb[(size_t)u1 * 128 + sl * 4]);
                uint2 v2 = *reinterpret_cast<const uint2*>(&xb[(size_t)u2 * 128 + sl * 4]);
                uint2 v3 = *reinterpret_cast<const uint2*>(&xb[(size_t)u3 * 128 + sl * 4]);
                a0 += blo(v0.x) + blo(v1.x) + blo(v2.x) + blo(v3.x);
                a1 += bhi(v0.x) + bhi(v1.x) + bhi(v2.x) + bhi(v3.x);
                a2 += blo(v0.y) + blo(v1.y) + blo(v2.y) + blo(v3.y);
                a3 += bhi(v0.y) + bhi(v1.y) + bhi(v2.y) + bhi(v3.y);
            }
            for (; p < e; ++p) {
                uint2 v0 = *reinterpret_cast<const uint2*>(&xb[(size_t)csr[p] * 128 + sl * 4]);
                a0 += blo(v0.x); a1 += bhi(v0.x); a2 += blo(v0.y); a3 += bhi(v0.y);
            }
            a0 *= sc; a1 *= sc; a2 *= sc; a3 *= sc;
        }
        ushort4 r4;
        r4.x = f2b(a0); r4.y = f2b(a1); r4.z = f2b(a2); r4.w = f2b(a3);
        *reinterpret_cast<ushort4*>(&At[lr * AST + sl * 4]) = r4;
    }
    // stage Bt = W1l^T
    #pragma unroll
    for (int i = 0; i < 8; ++i) {
        int c = t + 256 * i, r = c >> 4, k16 = c & 15;
        *reinterpret_cast<uint4*>(&Bt[r * AST + k16 * 8]) =
            *reinterpret_cast<const uint4*>(&w1lt[(size_t)r * 128 + k16 * 8]);
    }
    __syncthreads();
    #pragma unroll
    for (int ks = 0; ks < 4; ++ks) {
        bf16x8 a = *reinterpret_cast<const bf16x8*>(&At[(w * 16 + lrow) * AST + ks * 32 + lk * 8]);
        #pragma unroll
        for (int g = 0; g < 8; ++g) {
            bf16x8 b = *reinterpret_cast<const bf16x8*>(&Bt[(g * 16 + lrow) * AST + ks * 32 + lk * 8]);
            acc[g] = __builtin_amdgcn_mfma_f32_16x16x32_bf16(a, b, acc[g], 0, 0, 0);
        }
    }

    int orow = brow + w * 16 + lk * 4;
    #pragma unroll
    for (int g = 0; g < 8; ++g) {
        int gcol = g * 16 + lrow;
        float bv = b1[gcol];
        #pragma unroll
        for (int r = 0; r < 4; ++r) {
            int grow = orow + r;
            if (grow >= n) continue;
            float o = fmaxf(acc[g][r] + bv, 0.f);
            h[(size_t)grow * 128 + gcol] = f2b(o);
        }
    }
}

// ---------------- plain MFMA GEMM (layer-2 left): hl = h @ W2l -> bf16 ----------------
__global__ __launch_bounds__(256) void mg2_k(const ushort* __restrict__ A,
                                             const ushort* __restrict__ B,
                                             ushort* __restrict__ C, int n) {
    constexpr int AST = 136;
    __shared__ ushort At[64 * AST];
    __shared__ ushort Bt[64 * AST];
    int t = threadIdx.x;
    int brow = blockIdx.x * 64;
    int w = t >> 6, l = t & 63, lrow = l & 15, lk = l >> 4;

    f32x4 acc[4];
    #pragma unroll
    for (int g = 0; g < 4; ++g) acc[g] = (f32x4){0.f, 0.f, 0.f, 0.f};

    #pragma unroll
    for (int i = 0; i < 4; ++i) {
        int c = t + 256 * i, r = c >> 4, k16 = c & 15;
        int grow = brow + r;
        uint4 v = make_uint4(0, 0, 0, 0);
        if (grow < n) v = *reinterpret_cast<const uint4*>(&A[(size_t)grow * 128 + k16 * 8]);
        *reinterpret_cast<uint4*>(&At[r * AST + k16 * 8]) = v;
    }
    #pragma unroll
    for (int i = 0; i < 4; ++i) {
        int c = t + 256 * i, r = c >> 4, k16 = c & 15;
        *reinterpret_cast<uint4*>(&Bt[r * AST + k16 * 8]) =
            *reinterpret_cast<const uint4*>(&B[(size_t)r * 128 + k16 * 8]);
    }
    __syncthreads();
    #pragma unroll
    for (int ks = 0; ks < 4; ++ks) {
        bf16x8 a = *reinterpret_cast<const bf16x8*>(&At[(w * 16 + lrow) * AST + ks * 32 + lk * 8]);
        #pragma unroll
        for (int g = 0; g < 4; ++g) {
            bf16x8 b = *reinterpret_cast<const bf16x8*>(&Bt[(g * 16 + lrow) * AST + ks * 32 + lk * 8]);
            acc[g] = __builtin_amdgcn_mfma_f32_16x16x32_bf16(a, b, acc[g], 0, 0, 0);
        }
    }

    int orow = brow + w * 16 + lk * 4;
    #pragma unroll
    for (int g = 0; g < 4; ++g) {
        int gcol = g * 16 + lrow;
        #pragma unroll
        for (int r = 0; r < 4; ++r) {
            int grow = orow + r;
            if (grow >= n) continue;
            C[(size_t)grow * 64 + gcol] = f2b(acc[g][r]);
        }
    }
}

// ---------------- fused layer 2: out = h@W2r + gatherMean(hl) + b2 (fp32) ----------------
__global__ __launch_bounds__(256) void mg3_k(const ushort* __restrict__ h,
                                             const ushort* __restrict__ w2rt,
                                             const ushort* __restrict__ hl,
                                             const int* __restrict__ rowptr,
                                             const int* __restrict__ csr,
                                             const float* __restrict__ invd,
                                             const float* __restrict__ b2,
                                             float* __restrict__ out, int n) {
    constexpr int AST = 136;
    constexpr int TST = 66;            // add-tile stride (132B rows, 33-bank step)
    __shared__ ushort At[64 * AST];
    __shared__ ushort Bt[64 * AST];
    __shared__ ushort Tadd[64 * TST];
    int t = threadIdx.x;
    int brow = blockIdx.x * 64;
    int w = t >> 6, l = t & 63, lrow = l & 15, lk = l >> 4;

    f32x4 acc[4];
    #pragma unroll
    for (int g = 0; g < 4; ++g) acc[g] = (f32x4){0.f, 0.f, 0.f, 0.f};

    #pragma unroll
    for (int i = 0; i < 4; ++i) {
        int c = t + 256 * i, r = c >> 4, k16 = c & 15;
        int grow = brow + r;
        uint4 v = make_uint4(0, 0, 0, 0);
        if (grow < n) v = *reinterpret_cast<const uint4*>(&h[(size_t)grow * 128 + k16 * 8]);
        *reinterpret_cast<uint4*>(&At[r * AST + k16 * 8]) = v;
    }
    #pragma unroll
    for (int i = 0; i < 4; ++i) {
        int c = t + 256 * i, r = c >> 4, k16 = c & 15;
        *reinterpret_cast<uint4*>(&Bt[r * AST + k16 * 8]) =
            *reinterpret_cast<const uint4*>(&w2rt[(size_t)r * 128 + k16 * 8]);
    }
    __syncthreads();
    #pragma unroll
    for (int ks = 0; ks < 4; ++ks) {
        bf16x8 a = *reinterpret_cast<const bf16x8*>(&At[(w * 16 + lrow) * AST + ks * 32 + lk * 8]);
        #pragma unroll
        for (int g = 0; g < 4; ++g) {
            bf16x8 b = *reinterpret_cast<const bf16x8*>(&Bt[(g * 16 + lrow) * AST + ks * 32 + lk * 8]);
            acc[g] = __builtin_amdgcn_mfma_f32_16x16x32_bf16(a, b, acc[g], 0, 0, 0);
        }
    }

    // gather hl (64-wide rows): half-wave per node, lane owns 4B (2 bf16)
    int hw = t >> 5, sl = t & 31;
    for (int i = 0; i < 8; ++i) {
        int lr = i * 8 + hw;
        int node = brow + lr;
        float a0 = 0, a1 = 0;
        if (node < n) {
            int s = rowptr[node], e = rowptr[node + 1];
            float sc = invd[node];
            int p = s;
            for (; p + 4 <= e; p += 4) {
                int u0 = csr[p], u1 = csr[p + 1], u2 = csr[p + 2], u3 = csr[p + 3];
                uint v0 = *reinterpret_cast<const uint*>(&hl[(size_t)u0 * 64 + sl * 2]);
                uint v1 = *reinterpret_cast<const uint*>(&hl[(size_t)u1 * 64 + sl * 2]);
                uint v2 = *reinterpret_cast<const uint*>(&hl[(size_t)u2 * 64 + sl * 2]);
                uint v3 = *reinterpret_cast<const uint*>(&hl[(size_t)u3 * 64 + sl * 2]);
                a0 += blo(v0) + blo(v1) + blo(v2) + blo(v3);
                a1 += bhi(v0) + bhi(v1) + bhi(v2) + bhi(v3);
            }
            for (; p < e; ++p) {
                uint v0 = *reinterpret_cast<const uint*>(&hl[(size_t)csr[p] * 64 + sl * 2]);
                a0 += blo(v0); a1 += bhi(v0);
            }
            a0 *= sc; a1 *= sc;
        }
        ushort2 r2;
        r2.x = f2b(a0); r2.y = f2b(a1);
        *reinterpret_cast<ushort2*>(&Tadd[lr * TST + sl * 2]) = r2;
    }
    __syncthreads();

    int orow = brow + w * 16 + lk * 4;
    #pragma unroll
    for (int g = 0; g < 4; ++g) {
        int gcol = g * 16 + lrow;
        float bv = b2[gcol];
        #pragma unroll
        for (int r = 0; r < 4; ++r) {
            int grow = orow + r;
            if (grow >= n) continue;
            int lrr = w * 16 + lk * 4 + r;
            float o = acc[g][r] + bv + b2f(Tadd[lrr * TST + gcol]);
            out[(size_t)grow * 64 + gcol] = o;
        }
    }
}

extern "C" void kernel_launch(void* const* d_in, const int* in_sizes, int n_in,
                              void* d_out, int out_size, void* d_ws, size_t ws_size,
                              hipStream_t stream) {
    const float* x   = (const float*)d_in[0];
    const int*   edge= (const int*)d_in[1];
    const float* W1l = (const float*)d_in[2];
    const float* W1r = (const float*)d_in[3];
    const float* b1  = (const float*)d_in[4];
    const float* W2l = (const float*)d_in[5];
    const float* W2r = (const float*)d_in[6];
    const float* b2  = (const float*)d_in[7];
    float* out = (float*)d_out;

    const int N = in_sizes[0] / 128;
    const int E = in_sizes[1] / 2;
    const int* srcv = edge;
    const int* dstv = edge + E;

    char* p = (char*)d_ws;
    auto alloc = [&](size_t bytes) {
        char* q = p;
        p += ((bytes + 255) & ~(size_t)255);
        return q;
    };
    int*    cnt    = (int*)alloc((size_t)N * 4);
    int*    rowptr = (int*)alloc((size_t)(N + 1) * 4);
    int*    pos    = (int*)alloc((size_t)N * 4);
    int*    csr    = (int*)alloc((size_t)E * 4);
    float*  invd   = (float*)alloc((size_t)N * 4);
    int*    bsum   = (int*)alloc((size_t)256 * 4);
    int*    bktpos = (int*)alloc((size_t)256 * 4);
    uint2*  ebuf   = (uint2*)alloc((size_t)E * 8);
    ushort* xb     = (ushort*)alloc((size_t)N * 128 * 2);
    ushort* h      = (ushort*)alloc((size_t)N * 128 * 2);
    ushort* hl     = (ushort*)alloc((size_t)N * 64 * 2);
    ushort* w1lt   = (ushort*)alloc((size_t)16384 * 2);
    ushort* w1rt   = (ushort*)alloc((size_t)16384 * 2);
    ushort* w2lt   = (ushort*)alloc((size_t)8192 * 2);
    ushort* w2rt   = (ushort*)alloc((size_t)8192 * 2);

    int nb = (N + 1023) / 1024;
    int nbuckets = (N + 255) / 256;

    // dtype prep
    castx_k<<<(N * 32 + 255) / 256, 256, 0, stream>>>(x, xb, N * 32);
    prepw_k<<<192, 256, 0, stream>>>(W1l, W1r, W2l, W2r, w1lt, w1rt, w2lt, w2rt);

    // CSR build
    hipMemsetAsync(cnt, 0, (size_t)N * 4, stream);
    count_deg_k<<<(E + 255) / 256, 256, 0, stream>>>(dstv, cnt, E);
    blocksum_k<<<nb, 256, 0, stream>>>(cnt, bsum, N);
    bscan_k<<<1, 256, 0, stream>>>(bsum, nb);
    scanout_k<<<nb, 256, 0, stream>>>(cnt, bsum, rowptr, pos, invd, N, E);
    bucketbase_k<<<1, 256, 0, stream>>>(rowptr, bktpos, nbuckets);
    bucket_k<<<(E + 2047) / 2048, 256, 0, stream>>>(srcv, dstv, bktpos, ebuf, E);
    fill2_k<<<(E + 255) / 256, 256, 0, stream>>>(ebuf, pos, csr, E);

    int gb = (N + 63) / 64;
    // h = relu(xb@W1r + gatherMean(xb)@W1l + b1)
    mg1_k<<<gb, 256, 0, stream>>>(xb, w1rt, w1lt, rowptr, csr, invd, b1, h, N);
    // hl = h@W2l
    mg2_k<<<gb, 256, 0, stream>>>(h, w2lt, hl, N);
    // out = h@W2r + gatherMean(hl) + b2
    mg3_k<<<gb, 256, 0, stream>>>(h, w2rt, hl, rowptr, csr, invd, b2, out, N);
}